// Round 1
// baseline (69.372 us; speedup 1.0000x reference)
//
#include <hip/hip_runtime.h>

#define HID 16
#define NGATE 48   // 3*HID

__device__ __forceinline__ float fast_sigmoid(float x) {
    // 1/(1+e^-x); v_exp + v_rcp, ~1e-6 abs err, threshold is 9e-2
    return __builtin_amdgcn_rcpf(1.0f + __expf(-x));
}
__device__ __forceinline__ float fast_tanh(float x) {
    // 2/(1+e^-2x) - 1 ; exp overflow -> inf -> rcp -> 0 -> -1 (correct limit)
    return 2.0f * __builtin_amdgcn_rcpf(1.0f + __expf(-2.0f * x)) - 1.0f;
}

__global__ __launch_bounds__(256) void rssm_kernel(
    const float* __restrict__ prev_z,   // [B,3]
    const float* __restrict__ action,   // [B,1]
    const float* __restrict__ prev_h,   // [B,16]
    const float* __restrict__ W_ih,     // [48,4]
    const float* __restrict__ W_hh,     // [48,16]
    const float* __restrict__ b_ih,     // [48]
    const float* __restrict__ b_hh,     // [48]
    const float* __restrict__ W_mu,     // [3,16]
    const float* __restrict__ b_mu,     // [3]
    const float* __restrict__ W_lv,     // [3,16]
    const float* __restrict__ b_lv,     // [3]
    float* __restrict__ out_mu,         // [B,3]
    float* __restrict__ out_lv,         // [B,3]
    float* __restrict__ out_h,          // [B,16]
    int B)
{
    __shared__ float sW_ih[NGATE * 4];   // 192
    __shared__ float sW_hh[NGATE * HID]; // 768
    __shared__ float sb_ih[NGATE];
    __shared__ float sb_hh[NGATE];
    __shared__ float sW_mu[3 * HID];
    __shared__ float sW_lv[3 * HID];
    __shared__ float sb_mu[3];
    __shared__ float sb_lv[3];

    const int t = threadIdx.x;
    if (t < 192) sW_ih[t] = W_ih[t];
    for (int i = t; i < NGATE * HID; i += 256) sW_hh[i] = W_hh[i];
    if (t < NGATE) { sb_ih[t] = b_ih[t]; sb_hh[t] = b_hh[t]; }
    if (t < 48)    { sW_mu[t] = W_mu[t]; sW_lv[t] = W_lv[t]; }  // only 48 valid each
    if (t < 3)     { sb_mu[t] = b_mu[t]; sb_lv[t] = b_lv[t]; }
    __syncthreads();

    const int row = blockIdx.x * 256 + t;
    if (row >= B) return;

    // ---- inputs ----
    const float x0 = prev_z[row * 3 + 0];
    const float x1 = prev_z[row * 3 + 1];
    const float x2 = prev_z[row * 3 + 2];
    const float x3 = action[row];

    float h[HID];
    {
        const float4* hp = (const float4*)(prev_h + (size_t)row * HID);
        #pragma unroll
        for (int q = 0; q < 4; ++q) {
            float4 v = hp[q];
            h[q*4+0] = v.x; h[q*4+1] = v.y; h[q*4+2] = v.z; h[q*4+3] = v.w;
        }
    }

    // ---- r and z gates (sigmoid(i_g + h_g), biases folded together) ----
    float rg[HID], zg[HID];
    #pragma unroll
    for (int j = 0; j < HID; ++j) {
        // r: gate row j
        {
            const int g = j;
            float4 wi = *(const float4*)&sW_ih[g * 4];
            float acc = sb_ih[g] + sb_hh[g];
            acc = fmaf(wi.x, x0, acc); acc = fmaf(wi.y, x1, acc);
            acc = fmaf(wi.z, x2, acc); acc = fmaf(wi.w, x3, acc);
            #pragma unroll
            for (int k = 0; k < 4; ++k) {
                float4 wh = *(const float4*)&sW_hh[g * HID + k * 4];
                acc = fmaf(wh.x, h[k*4+0], acc); acc = fmaf(wh.y, h[k*4+1], acc);
                acc = fmaf(wh.z, h[k*4+2], acc); acc = fmaf(wh.w, h[k*4+3], acc);
            }
            rg[j] = fast_sigmoid(acc);
        }
        // z: gate row 16+j
        {
            const int g = HID + j;
            float4 wi = *(const float4*)&sW_ih[g * 4];
            float acc = sb_ih[g] + sb_hh[g];
            acc = fmaf(wi.x, x0, acc); acc = fmaf(wi.y, x1, acc);
            acc = fmaf(wi.z, x2, acc); acc = fmaf(wi.w, x3, acc);
            #pragma unroll
            for (int k = 0; k < 4; ++k) {
                float4 wh = *(const float4*)&sW_hh[g * HID + k * 4];
                acc = fmaf(wh.x, h[k*4+0], acc); acc = fmaf(wh.y, h[k*4+1], acc);
                acc = fmaf(wh.z, h[k*4+2], acc); acc = fmaf(wh.w, h[k*4+3], acc);
            }
            zg[j] = fast_sigmoid(acc);
        }
    }

    // ---- n gate (tanh(i_n + r * h_n)) and new h ----
    float hn[HID];
    #pragma unroll
    for (int j = 0; j < HID; ++j) {
        const int g = 2 * HID + j;
        float4 wi = *(const float4*)&sW_ih[g * 4];
        float ai = sb_ih[g];
        ai = fmaf(wi.x, x0, ai); ai = fmaf(wi.y, x1, ai);
        ai = fmaf(wi.z, x2, ai); ai = fmaf(wi.w, x3, ai);
        float ah = sb_hh[g];
        #pragma unroll
        for (int k = 0; k < 4; ++k) {
            float4 wh = *(const float4*)&sW_hh[g * HID + k * 4];
            ah = fmaf(wh.x, h[k*4+0], ah); ah = fmaf(wh.y, h[k*4+1], ah);
            ah = fmaf(wh.z, h[k*4+2], ah); ah = fmaf(wh.w, h[k*4+3], ah);
        }
        const float nv = fast_tanh(fmaf(rg[j], ah, ai));
        hn[j] = fmaf(zg[j], h[j] - nv, nv);   // (1-z)*n + z*h
    }

    // ---- heads: mu, logvar ----
    #pragma unroll
    for (int m = 0; m < 3; ++m) {
        float am = sb_mu[m];
        float al = sb_lv[m];
        #pragma unroll
        for (int k = 0; k < HID; ++k) {
            am = fmaf(sW_mu[m * HID + k], hn[k], am);
            al = fmaf(sW_lv[m * HID + k], hn[k], al);
        }
        out_mu[row * 3 + m] = am;
        out_lv[row * 3 + m] = fminf(fmaxf(al, -5.0f), 5.0f);
    }

    // ---- store h ----
    float4* ho = (float4*)(out_h + (size_t)row * HID);
    #pragma unroll
    for (int q = 0; q < 4; ++q)
        ho[q] = make_float4(hn[q*4+0], hn[q*4+1], hn[q*4+2], hn[q*4+3]);
}

extern "C" void kernel_launch(void* const* d_in, const int* in_sizes, int n_in,
                              void* d_out, int out_size, void* d_ws, size_t ws_size,
                              hipStream_t stream) {
    const float* prev_z = (const float*)d_in[0];
    const float* action = (const float*)d_in[1];
    const float* prev_h = (const float*)d_in[2];
    const float* W_ih   = (const float*)d_in[3];
    const float* W_hh   = (const float*)d_in[4];
    const float* b_ih   = (const float*)d_in[5];
    const float* b_hh   = (const float*)d_in[6];
    const float* W_mu   = (const float*)d_in[7];
    const float* b_mu   = (const float*)d_in[8];
    const float* W_lv   = (const float*)d_in[9];
    const float* b_lv   = (const float*)d_in[10];

    const int B = in_sizes[0] / 3;
    float* out    = (float*)d_out;
    float* out_mu = out;
    float* out_lv = out + (size_t)3 * B;
    float* out_h  = out + (size_t)6 * B;

    const int blocks = (B + 255) / 256;
    rssm_kernel<<<blocks, 256, 0, stream>>>(prev_z, action, prev_h,
                                            W_ih, W_hh, b_ih, b_hh,
                                            W_mu, b_mu, W_lv, b_lv,
                                            out_mu, out_lv, out_h, B);
}